// Round 7
// baseline (187.582 us; speedup 1.0000x reference)
//
#include <hip/hip_runtime.h>
#include <math.h>

#define N_ 32
#define C_ 512
#define CR_ 64
#define HW_ 3136
#define HW4_ 784
#define RPB_ 8          // rows per block
#define BPS_ 64         // blocks per sample = C_/RPB_
constexpr float EPS = 1e-5f;

typedef float f4 __attribute__((ext_vector_type(4)));

#define LD_A(p)   __hip_atomic_load((p), __ATOMIC_RELAXED, __HIP_MEMORY_SCOPE_AGENT)
#define ST_A(p,v) __hip_atomic_store((p), (v), __ATOMIC_RELAXED, __HIP_MEMORY_SCOPE_AGENT)

// System-scope non-temporal store: nt (no L2 alloc) + sc0 sc1 (system scope)
// -> intended to bypass Infinity Cache allocation so x stays L3-resident.
__device__ __forceinline__ void store_nt_bypass(const f4 v, f4* p) {
    asm volatile("global_store_dwordx4 %0, %1, off sc0 sc1 nt"
                 :: "v"(p), "v"(v) : "memory");
}

// ---------------- Kernel A: pool + (last block per sample) gate ----------------
// 2048 blocks x 256 thr; each wave pools 2 rows (wave-reduce only, no barriers).
// The 64th block to finish a sample computes that sample's gate inline.
__global__ __launch_bounds__(256) void poolgate_kernel(
    const float* __restrict__ x,
    const float* __restrict__ w1, const float* __restrict__ b1,
    const float* __restrict__ gn1_w, const float* __restrict__ gn1_b,
    const float* __restrict__ w2, const float* __restrict__ b2,
    const float* __restrict__ gn2_w, const float* __restrict__ gn2_b,
    float* __restrict__ pooled, float* __restrict__ gate,
    int* __restrict__ cnt)
{
    const int b = blockIdx.x;            // 0..2047
    const int n = b / BPS_;              // sample
    const int tid = threadIdx.x;
    const int wid = tid >> 6, lane = tid & 63;
    const int row0 = b * RPB_;

    // ---- pool: wave w handles rows row0+2w, row0+2w+1 ----
    #pragma unroll
    for (int k = 0; k < 2; ++k) {
        const int row = row0 + wid * 2 + k;
        const f4* xr = reinterpret_cast<const f4*>(x + (size_t)row * HW_);
        float acc = 0.f;
        for (int j = lane; j < HW4_; j += 64) {
            f4 v = xr[j];
            acc += (v.x + v.y) + (v.z + v.w);
        }
        for (int o = 32; o; o >>= 1) acc += __shfl_down(acc, o, 64);
        if (lane == 0) ST_A(&pooled[row], acc * (1.0f / HW_));
    }
    __syncthreads();

    __shared__ int lastFlag;
    if (tid == 0) {
        const int old = __hip_atomic_fetch_add(&cnt[n], 1, __ATOMIC_ACQ_REL,
                                               __HIP_MEMORY_SCOPE_AGENT);
        lastFlag = (old == BPS_ - 1);
    }
    __syncthreads();
    if (!lastFlag) return;

    // ---- gate for sample n (256 threads) ----
    __shared__ float sp[C_];
    __shared__ float sh[CR_];
    __shared__ float sred[4];
    const int base = n * C_;
    sp[tid]       = LD_A(&pooled[base + tid]);
    sp[tid + 256] = LD_A(&pooled[base + 256 + tid]);
    __syncthreads();

    // h[r] = dot(sp, w1[r,:]) + b1[r] ; 4 threads per output r
    {
        const int r = tid >> 2, l4 = tid & 3;
        float a = 0.f;
        for (int cc = l4; cc < C_; cc += 4) a += sp[cc] * w1[r * C_ + cc];
        a += __shfl_xor(a, 1, 64);
        a += __shfl_xor(a, 2, 64);
        if (l4 == 0) sh[r] = a + b1[r];
    }
    __syncthreads();

    // GroupNorm(1) over 64 + ELU (first wave)
    if (tid < 64) {
        const float v = sh[tid];
        float s = v;
        for (int o = 32; o; o >>= 1) s += __shfl_xor(s, o, 64);
        const float mu = s * (1.0f / CR_);
        const float d = v - mu;
        float vv = d * d;
        for (int o = 32; o; o >>= 1) vv += __shfl_xor(vv, o, 64);
        float xn = d * rsqrtf(vv * (1.0f / CR_) + EPS) * gn1_w[tid] + gn1_b[tid];
        sh[tid] = xn > 0.f ? xn : expm1f(xn);   // ELU alpha=1
    }
    __syncthreads();

    // g[c] for c = tid, tid+256
    float g0 = b2[tid], g1 = b2[tid + 256];
    #pragma unroll 8
    for (int r = 0; r < CR_; ++r) {
        g0 += sh[r] * w2[tid * CR_ + r];
        g1 += sh[r] * w2[(tid + 256) * CR_ + r];
    }
    // GroupNorm(1) over 512
    float s = g0 + g1;
    for (int o = 32; o; o >>= 1) s += __shfl_xor(s, o, 64);
    if ((tid & 63) == 0) sred[tid >> 6] = s;
    __syncthreads();
    const float mu = (sred[0] + sred[1] + sred[2] + sred[3]) * (1.0f / C_);
    const float d0 = g0 - mu, d1 = g1 - mu;
    float vv = d0 * d0 + d1 * d1;
    for (int o = 32; o; o >>= 1) vv += __shfl_xor(vv, o, 64);
    __syncthreads();
    if ((tid & 63) == 0) sred[tid >> 6] = vv;
    __syncthreads();
    const float rstd = rsqrtf((sred[0] + sred[1] + sred[2] + sred[3]) * (1.0f / C_) + EPS);
    const float xn0 = d0 * rstd * gn2_w[tid] + gn2_b[tid];
    const float xn1 = d1 * rstd * gn2_w[tid + 256] + gn2_b[tid + 256];
    ST_A(&gate[base + tid],       1.f / (1.f + expf(-xn0)));
    ST_A(&gate[base + tid + 256], 1.f / (1.f + expf(-xn1)));
}

// ---------------- Kernel B: broadcast scale ----------------
// 2048 blocks x 256 thr; wave w scales rows row0+2w, row0+2w+1.
// Output via system-scope nt stores (MALL bypass attempt).
__global__ __launch_bounds__(256) void scale_kernel(const float* __restrict__ x,
                                                    const float* __restrict__ gate,
                                                    float* __restrict__ out) {
    const int b = blockIdx.x;
    const int tid = threadIdx.x;
    const int wid = tid >> 6, lane = tid & 63;
    const int row0 = b * RPB_;
    #pragma unroll
    for (int k = 0; k < 2; ++k) {
        const int row = row0 + wid * 2 + k;
        const float g = gate[row];
        const f4* xr = reinterpret_cast<const f4*>(x + (size_t)row * HW_);
        f4* orow = reinterpret_cast<f4*>(out + (size_t)row * HW_);
        for (int j = lane; j < HW4_; j += 64) {
            f4 v = xr[j];
            v *= g;
            store_nt_bypass(v, &orow[j]);
        }
    }
}

extern "C" void kernel_launch(void* const* d_in, const int* in_sizes, int n_in,
                              void* d_out, int out_size, void* d_ws, size_t ws_size,
                              hipStream_t stream) {
    const float* x     = (const float*)d_in[0];
    const float* w1    = (const float*)d_in[1];
    const float* b1    = (const float*)d_in[2];
    const float* gn1_w = (const float*)d_in[3];
    const float* gn1_b = (const float*)d_in[4];
    const float* w2    = (const float*)d_in[5];
    const float* b2    = (const float*)d_in[6];
    const float* gn2_w = (const float*)d_in[7];
    const float* gn2_b = (const float*)d_in[8];
    float* out = (float*)d_out;

    float* pooled = (float*)d_ws;              // N_*C_ floats
    float* gate   = pooled + N_ * C_;          // N_*C_ floats
    int*   cnt    = (int*)(gate + N_ * C_);    // N_ ints

    hipMemsetAsync(cnt, 0, N_ * sizeof(int), stream);

    poolgate_kernel<<<(N_ * C_) / RPB_, 256, 0, stream>>>(
        x, w1, b1, gn1_w, gn1_b, w2, b2, gn2_w, gn2_b, pooled, gate, cnt);
    scale_kernel<<<(N_ * C_) / RPB_, 256, 0, stream>>>(x, gate, out);
}